// Round 2
// baseline (730.800 us; speedup 1.0000x reference)
//
#include <hip/hip_runtime.h>

#define NN 100000
#define NE 1600000
#define D 128
#define KTOT 384          // fp16 single-precision: [b1(h) | b2(nb1) | b3(nb2)]
#define LN_EPS 1e-5f

#define PITCH_US 200      // ushorts per staged row (192 + 8 pad); 100 dw, 100%32=4
#define PITCH_DW 100

#define SCAN_CHUNK 2048
#define NSB 49            // ceil(NN / SCAN_CHUNK)

#define NBK 98            // dst buckets (dst >> 10), 1024 nodes each
#define BCAP 20480        // slots per bucket (avg fill 16.3K, sigma ~126)

#define NCH 8             // dim chunks (16 dims = 32B each); chunk c -> XCD c via blockIdx%8
#define CHW (NN * 8)      // dwords per chunk region (800000)

// ---- workspace layout (bytes) ----
#define WS_OFF_OFF   0          // 100352 int (pad absorbs tail writes)
#define WS_OFF_CUR   401408     // 100352 int (memset 0; post-scatter = per-node count)
#define WS_OFF_BSUM  802816     // 64 int
#define WS_OFF_GCUR  803072     // 128 int (memset 0)
#define WS_OFF_WCBF  803584     // 128*384 u16 (region reserved for 640)
#define WS_OFF_ESRC  967680     // 1.7M int
#define WS_OFF_GBUF  7768064    // 98*20480*8 = 16056320, then reused as h16T
#define WS_OFF_H16   7768064    // NN*128 fp16 = 25600000 (chunk-major)
#define WS_OFF_NB1   33368064   // NN*128 fp16 = 25600000 (chunk-major, end 58968064)

typedef __attribute__((ext_vector_type(8))) _Float16 f16x8;
typedef __attribute__((ext_vector_type(2))) _Float16 f16x2;
typedef __attribute__((ext_vector_type(4))) float f32x4;

__device__ __forceinline__ unsigned short f2h(float f) {
    _Float16 h = (_Float16)f;                  // v_cvt_f16_f32, RN
    unsigned short s; __builtin_memcpy(&s, &h, 2); return s;
}
__device__ __forceinline__ f16x2 u2h2(unsigned u) {
    f16x2 h; __builtin_memcpy(&h, &u, 4); return h;
}

// h (fp32, node-major) -> h16T (fp16 pairs, chunk-major: [c][node][8 dw])
__global__ void k_prep(const float* __restrict__ h, unsigned int* __restrict__ hT) {
    int j = blockIdx.x * blockDim.x + threadIdx.x;   // 6.4M dwords, output-centric
    int c = j / CHW;
    int rem = j - c * CHW;
    int n = rem >> 3, p = rem & 7;
    float2 v = reinterpret_cast<const float2*>(h)[(size_t)n * 64 + c * 8 + p];
    hT[j] = (unsigned)f2h(v.x) | ((unsigned)f2h(v.y) << 16);
}

// pass 1: scan int(deg) per 2048-chunk -> off (local excl), block total -> bsum
__global__ __launch_bounds__(256) void k_scan1(const float* __restrict__ deg,
                                               int* __restrict__ off,
                                               int* __restrict__ bsum) {
    __shared__ int lds[256];
    int t = threadIdx.x, b = blockIdx.x;
    int base = b * SCAN_CHUNK + t * 8;
    int v[8];
    if (base < NN) {   // NN % 8 == 0
        float4 a0 = reinterpret_cast<const float4*>(deg + base)[0];
        float4 a1 = reinterpret_cast<const float4*>(deg + base)[1];
        v[0] = __float2int_rn(a0.x); v[1] = __float2int_rn(a0.y);
        v[2] = __float2int_rn(a0.z); v[3] = __float2int_rn(a0.w);
        v[4] = __float2int_rn(a1.x); v[5] = __float2int_rn(a1.y);
        v[6] = __float2int_rn(a1.z); v[7] = __float2int_rn(a1.w);
    } else {
        #pragma unroll
        for (int j = 0; j < 8; ++j) v[j] = 0;
    }
    int s = 0;
    #pragma unroll
    for (int j = 0; j < 8; ++j) s += v[j];
    lds[t] = s;
    __syncthreads();
    for (int ofs = 1; ofs < 256; ofs <<= 1) {
        int x = (t >= ofs) ? lds[t - ofs] : 0;
        __syncthreads();
        lds[t] += x;
        __syncthreads();
    }
    int excl = (t == 0) ? 0 : lds[t - 1];
    #pragma unroll
    for (int j = 0; j < 8; ++j) { off[base + j] = excl; excl += v[j]; }
    if (t == 255) bsum[b] = lds[255];
}

__global__ void k_scan2(int* __restrict__ bsum) {
    int t = threadIdx.x;
    int v = (t < NSB) ? bsum[t] : 0;
    #pragma unroll
    for (int ofs = 1; ofs < 64; ofs <<= 1) {
        int x = __shfl_up(v, ofs, 64);
        if (t >= ofs) v += x;
    }
    int excl = __shfl_up(v, 1, 64);
    if (t == 0) excl = 0;
    if (t < NSB) bsum[t] = excl;
    if (t == NSB - 1) bsum[NSB] = v;
}

__global__ void k_scan3(int* __restrict__ off, const int* __restrict__ bsum) {
    int i = blockIdx.x * blockDim.x + threadIdx.x;
    if (i < NN) off[i] += bsum[i >> 11];
    if (i == 0) off[NN] = bsum[NSB];
}

// binning pass A: edges -> 98 dst-range buckets, LDS-aggregated ranks
__global__ __launch_bounds__(256) void k_bin(const int* __restrict__ src,
                                             const int* __restrict__ dst,
                                             int* __restrict__ gcur,
                                             int2* __restrict__ gbuf) {
    __shared__ int bcnt[NBK];
    __shared__ int bbase[NBK];
    int t = threadIdx.x;
    if (t < NBK) bcnt[t] = 0;
    __syncthreads();
    int e0 = blockIdx.x * 2048;
    int s[8], d[8], r[8];
    #pragma unroll
    for (int it = 0; it < 8; ++it) {
        int e = e0 + it * 256 + t;
        bool ok = e < NE;
        s[it] = ok ? src[e] : 0;
        d[it] = ok ? dst[e] : -1;
        r[it] = ok ? atomicAdd(&bcnt[d[it] >> 10], 1) : 0;
    }
    __syncthreads();
    if (t < NBK) bbase[t] = atomicAdd(&gcur[t], bcnt[t]);
    __syncthreads();
    #pragma unroll
    for (int it = 0; it < 8; ++it) {
        if (d[it] >= 0) {
            int bk = d[it] >> 10;
            gbuf[(size_t)bk * BCAP + bbase[bk] + r[it]] = make_int2(s[it], d[it]);
        }
    }
}

// scatter pass B: one block per bucket; esrc/cur writes stay in a ~70KB L2 window
__global__ __launch_bounds__(1024) void k_scatter2(const int2* __restrict__ gbuf,
                                                   const int* __restrict__ gcur,
                                                   const int* __restrict__ off,
                                                   int* __restrict__ cur,
                                                   int* __restrict__ esrc) {
    int b = blockIdx.x;
    int nb = gcur[b];
    const int2* bb = gbuf + (size_t)b * BCAP;
    for (int i = threadIdx.x; i < nb; i += 1024) {
        int2 e = bb[i];
        int p = off[e.y] + atomicAdd(&cur[e.y], 1);
        esrc[p] = e.x;
    }
}

// combined weights -> fp16, [o][384]: segs {b1, b2, b3}
__global__ void k_weights(const float* __restrict__ Ws, const float* __restrict__ W1,
                          const float* __restrict__ Whp, const float* __restrict__ W2,
                          const float* __restrict__ logits, unsigned short* __restrict__ wcbf) {
    int idx = blockIdx.x * blockDim.x + threadIdx.x;
    if (idx >= D * D) return;
    int o = idx >> 7, k = idx & 127;
    float s0 = 2.f / (1.f + __expf(-logits[0]));
    float s1 = 2.f / (1.f + __expf(-logits[1]));
    float s2 = 2.f / (1.f + __expf(-logits[2]));
    float s3 = 2.f / (1.f + __expf(-logits[3]));
    unsigned short b1 = f2h(s0 * Ws[idx] + s2 * Whp[idx]);
    unsigned short b2 = f2h(s1 * W1[idx] - s2 * Whp[idx]);
    unsigned short b3 = f2h(s3 * W2[idx]);
    size_t base = (size_t)o * KTOT + k;
    wcbf[base]       = b1;   // h
    wcbf[base + 128] = b2;   // nb1
    wcbf[base + 256] = b3;   // nb2
}

// XCD-sharded hop: block b handles dim-chunk c = b&7 (3.2MB slice, L2-resident
// on its XCD) for 4 nodes (one per wave). 4-lane groups: one dwordx2 load
// instruction gathers 16 edges x 32B. esrc streamed nontemporal.
// INTERLEAVED=true: chunk c writes nb2 dims [16c,16c+16) into out row's 2nd
// half at dword 64+c*8 (natural order; gemm block reads then overwrites).
template <bool INTERLEAVED>
__global__ __launch_bounds__(256) void k_hop(const unsigned int* __restrict__ in,
                                             unsigned int* __restrict__ outp,
                                             const int* __restrict__ off,
                                             const int* __restrict__ cnt_arr,
                                             const int* __restrict__ esrc,
                                             const float* __restrict__ deg) {
    int c = blockIdx.x & 7;
    int w = (blockIdx.x >> 3) * 4 + (threadIdx.x >> 6);
    int lane = threadIdx.x & 63;
    int g = lane >> 2, p2 = lane & 3;
    const unsigned* bin = in + (size_t)c * CHW;
    int beg = __builtin_amdgcn_readfirstlane(off[w]);
    int cnt = __builtin_amdgcn_readfirstlane(cnt_arr[w]);
    float a0 = 0.f, a1 = 0.f, a2 = 0.f, a3 = 0.f;
    for (int bs = 0; bs < cnt; bs += 64) {
        int m = cnt - bs; if (m > 64) m = 64;
        int ev = __builtin_nontemporal_load(esrc + beg + bs + (lane < m ? lane : 0));
        for (int j = 0; j < m; j += 32) {
            int idx0 = j + g;
            bool ok0 = idx0 < m;
            int sv0 = __shfl(ev, ok0 ? idx0 : 0, 64);
            uint2 A = *reinterpret_cast<const uint2*>(bin + (size_t)sv0 * 8 + p2 * 2);
            uint2 B; B.x = 0u; B.y = 0u;
            if (j + 16 < m) {              // wave-uniform branch
                int idx1 = j + 16 + g;
                bool ok1 = idx1 < m;
                int sv1 = __shfl(ev, ok1 ? idx1 : 0, 64);
                B = *reinterpret_cast<const uint2*>(bin + (size_t)sv1 * 8 + p2 * 2);
                if (!ok1) { B.x = 0u; B.y = 0u; }
            }
            if (!ok0) { A.x = 0u; A.y = 0u; }
            f16x2 v0 = u2h2(A.x), v1 = u2h2(A.y), v2 = u2h2(B.x), v3 = u2h2(B.y);
            a0 += (float)v0.x + (float)v2.x;
            a1 += (float)v0.y + (float)v2.y;
            a2 += (float)v1.x + (float)v3.x;
            a3 += (float)v1.y + (float)v3.y;
        }
    }
    #pragma unroll
    for (int o = 4; o < 64; o <<= 1) {
        a0 += __shfl_xor(a0, o, 64);
        a1 += __shfl_xor(a1, o, 64);
        a2 += __shfl_xor(a2, o, 64);
        a3 += __shfl_xor(a3, o, 64);
    }
    if (lane < 4) {
        float inv = 1.0f / deg[w];
        uint2 pk;
        pk.x = (unsigned)f2h(a0 * inv) | ((unsigned)f2h(a1 * inv) << 16);
        pk.y = (unsigned)f2h(a2 * inv) | ((unsigned)f2h(a3 * inv) << 16);
        if (INTERLEAVED)
            *reinterpret_cast<uint2*>(outp + (size_t)w * 128 + 64 + c * 8 + p2 * 2) = pk;
        else
            *reinterpret_cast<uint2*>(outp + (size_t)c * CHW + (size_t)w * 8 + p2 * 2) = pk;
    }
}

// MFMA GEMM (M=32/block, N=128, K=384 in two 192-K LDS chunks) + fused LN.
// h16/nb1 now chunk-major: src reads are 1KB-contiguous per (it,c) stripe.
__global__ __launch_bounds__(256) void k_gemm_ln(
    const unsigned int* __restrict__ hT,
    const unsigned int* __restrict__ nb1T,
    const unsigned short* __restrict__ wcbf, const float* __restrict__ bias,
    const float* __restrict__ gamma, const float* __restrict__ beta,
    float* __restrict__ out) {
    __shared__ __align__(16) unsigned short Xs[32 * PITCH_US];   // 12800 B
    __shared__ float part_s[4][32];
    __shared__ float part_q[4][32];
    __shared__ float mu_s[32], rs_s[32];
    unsigned int* Xs_u = reinterpret_cast<unsigned int*>(Xs);
    const unsigned int* out_u = reinterpret_cast<const unsigned int*>(out);

    const int t = threadIdx.x;
    const int wv = t >> 6, lane = t & 63;
    const int lm = lane & 15, quad = lane >> 4;
    const int node0 = blockIdx.x * 32;
    const int obase = wv * 32;

    f32x4 acc[2][2] = {};

    #pragma unroll
    for (int cc = 0; cc < 2; ++cc) {
        if (cc == 0) {
            // ---- stage chunk 0: h dims 0..127 (dw 0..63), nb1 dims 0..63 (dw 64..95)
            #pragma unroll
            for (int it = 0; it < 8; ++it) {
                int i = t + 256 * it;
                int c = i >> 8, row = (i >> 3) & 31, p = i & 7;
                Xs_u[row * PITCH_DW + c * 8 + p] =
                    hT[(size_t)c * CHW + (size_t)(node0 + row) * 8 + p];
            }
            #pragma unroll
            for (int it = 0; it < 4; ++it) {
                int i = t + 256 * it;
                int c = i >> 8, row = (i >> 3) & 31, p = i & 7;
                Xs_u[row * PITCH_DW + 64 + c * 8 + p] =
                    nb1T[(size_t)c * CHW + (size_t)(node0 + row) * 8 + p];
            }
        } else {
            // ---- stage chunk 1: nb1 dims 64..127 (dw 0..31), nb2 (dw 32..95, from out)
            #pragma unroll
            for (int it = 0; it < 4; ++it) {
                int i = t + 256 * it;
                int c = i >> 8, row = (i >> 3) & 31, p = i & 7;
                Xs_u[row * PITCH_DW + c * 8 + p] =
                    nb1T[(size_t)(4 + c) * CHW + (size_t)(node0 + row) * 8 + p];
            }
            #pragma unroll
            for (int it = 0; it < 8; ++it) {
                int i = t + 256 * it;
                int row = i >> 6, d = i & 63;
                Xs_u[row * PITCH_DW + 32 + d] = out_u[(size_t)(node0 + row) * 128 + 64 + d];
            }
        }
        __syncthreads();

        f16x8 bfr[2][6];
        #pragma unroll
        for (int nt = 0; nt < 2; ++nt) {
            const unsigned short* wp =
                wcbf + (size_t)(obase + nt * 16 + lm) * KTOT + cc * 192 + quad * 8;
            #pragma unroll
            for (int s = 0; s < 6; ++s)
                bfr[nt][s] = *reinterpret_cast<const f16x8*>(wp + s * 32);
        }
        #pragma unroll
        for (int s = 0; s < 6; ++s) {
            int koff = s * 32 + quad * 8;
            f16x8 a0 = *reinterpret_cast<const f16x8*>(&Xs[(0 * 16 + lm) * PITCH_US + koff]);
            f16x8 a1 = *reinterpret_cast<const f16x8*>(&Xs[(1 * 16 + lm) * PITCH_US + koff]);
            acc[0][0] = __builtin_amdgcn_mfma_f32_16x16x32_f16(a0, bfr[0][s], acc[0][0], 0, 0, 0);
            acc[0][1] = __builtin_amdgcn_mfma_f32_16x16x32_f16(a0, bfr[1][s], acc[0][1], 0, 0, 0);
            acc[1][0] = __builtin_amdgcn_mfma_f32_16x16x32_f16(a1, bfr[0][s], acc[1][0], 0, 0, 0);
            acc[1][1] = __builtin_amdgcn_mfma_f32_16x16x32_f16(a1, bfr[1][s], acc[1][1], 0, 0, 0);
        }
        __syncthreads();   // safe to restage / proceed
    }

    // ---- LN: add bias; per-row partial sums via lm-butterfly; cross-wave via LDS
    float bv0 = bias[obase + lm], bv1 = bias[obase + 16 + lm];
    #pragma unroll
    for (int mt = 0; mt < 2; ++mt) {
        float s[4], q[4];
        #pragma unroll
        for (int r = 0; r < 4; ++r) {
            float v0 = acc[mt][0][r] + bv0;
            float v1 = acc[mt][1][r] + bv1;
            acc[mt][0][r] = v0;  acc[mt][1][r] = v1;
            s[r] = v0 + v1;
            q[r] = v0 * v0 + v1 * v1;
        }
        #pragma unroll
        for (int off = 1; off < 16; off <<= 1) {
            #pragma unroll
            for (int r = 0; r < 4; ++r) {
                s[r] += __shfl_xor(s[r], off, 64);
                q[r] += __shfl_xor(q[r], off, 64);
            }
        }
        if (lm == 0) {
            #pragma unroll
            for (int r = 0; r < 4; ++r) {
                part_s[wv][mt * 16 + quad * 4 + r] = s[r];
                part_q[wv][mt * 16 + quad * 4 + r] = q[r];
            }
        }
    }
    __syncthreads();
    if (t < 32) {
        float s = part_s[0][t] + part_s[1][t] + part_s[2][t] + part_s[3][t];
        float q = part_q[0][t] + part_q[1][t] + part_q[2][t] + part_q[3][t];
        float m = s * (1.f / 128.f);
        float var = q * (1.f / 128.f) - m * m;
        mu_s[t] = m;
        rs_s[t] = rsqrtf(var + LN_EPS);
    }
    __syncthreads();

    float g0 = gamma[obase + lm], g1 = gamma[obase + 16 + lm];
    float e0 = beta[obase + lm],  e1 = beta[obase + 16 + lm];
    #pragma unroll
    for (int mt = 0; mt < 2; ++mt) {
        #pragma unroll
        for (int r = 0; r < 4; ++r) {
            int lrow = mt * 16 + quad * 4 + r;
            float mu = mu_s[lrow], rs = rs_s[lrow];
            size_t ro = (size_t)(node0 + lrow) * D;
            out[ro + obase + lm]      = (acc[mt][0][r] - mu) * rs * g0 + e0;
            out[ro + obase + 16 + lm] = (acc[mt][1][r] - mu) * rs * g1 + e1;
        }
    }
}

extern "C" void kernel_launch(void* const* d_in, const int* in_sizes, int n_in,
                              void* d_out, int out_size, void* d_ws, size_t ws_size,
                              hipStream_t stream) {
    const float* h      = (const float*)d_in[0];
    const int*   ei     = (const int*)d_in[1];
    const float* deg    = (const float*)d_in[2];
    const float* Wself  = (const float*)d_in[3];
    const float* Wnb1   = (const float*)d_in[4];
    const float* Whp    = (const float*)d_in[5];
    const float* Wnb2   = (const float*)d_in[6];
    const float* bias   = (const float*)d_in[7];
    const float* logits = (const float*)d_in[8];
    const float* gamma  = (const float*)d_in[9];
    const float* beta   = (const float*)d_in[10];
    float* out = (float*)d_out;

    char* ws = (char*)d_ws;
    int* off                 = (int*)(ws + WS_OFF_OFF);
    int* cur                 = (int*)(ws + WS_OFF_CUR);
    int* bsum                = (int*)(ws + WS_OFF_BSUM);
    int* gcur                = (int*)(ws + WS_OFF_GCUR);
    unsigned short* wcbf     = (unsigned short*)(ws + WS_OFF_WCBF);
    int* esrc                = (int*)(ws + WS_OFF_ESRC);
    int2* gbuf               = (int2*)(ws + WS_OFF_GBUF);
    unsigned int* h16        = (unsigned int*)(ws + WS_OFF_H16);
    unsigned int* nb1u       = (unsigned int*)(ws + WS_OFF_NB1);

    const int* src = ei;
    const int* dst = ei + NE;

    hipMemsetAsync(cur, 0, NN * sizeof(int), stream);
    hipMemsetAsync(gcur, 0, NBK * sizeof(int), stream);

    k_weights<<<64, 256, 0, stream>>>(Wself, Wnb1, Whp, Wnb2, logits, wcbf);
    k_scan1<<<NSB, 256, 0, stream>>>(deg, off, bsum);
    k_scan2<<<1, 64, 0, stream>>>(bsum);
    k_scan3<<<(NN + 255) / 256, 256, 0, stream>>>(off, bsum);
    k_bin<<<(NE + 2047) / 2048, 256, 0, stream>>>(src, dst, gcur, gbuf);
    k_scatter2<<<NBK, 1024, 0, stream>>>(gbuf, gcur, off, cur, esrc);

    // prep AFTER scatter2: h16T overlays the (now dead) gbuf region
    k_prep<<<25000, 256, 0, stream>>>(h, h16);

    // hops: 8 chunks x 25000 node-groups; chunk = blockIdx%8 -> XCD-pinned slice
    k_hop<false><<<NCH * (NN / 4), 256, 0, stream>>>(h16, nb1u, off, cur, esrc, deg);
    k_hop<true><<<NCH * (NN / 4), 256, 0, stream>>>(nb1u, (unsigned int*)out, off, cur, esrc, deg);

    k_gemm_ln<<<NN / 32, 256, 0, stream>>>(h16, nb1u, wcbf, bias, gamma, beta, out);
}

// Round 3
// 376.013 us; speedup vs baseline: 1.9436x; 1.9436x over previous
//
#include <hip/hip_runtime.h>

#define NN 100000
#define NE 1600000
#define D 128
#define KTOT 384          // fp16 single-precision: [b1(h) | b2(nb1) | b3(nb2)]
#define LN_EPS 1e-5f

#define PITCH_US 200      // ushorts per staged row (192 + 8 pad); 100 dw, 100%32=4
#define PITCH_DW 100

#define SCAN_CHUNK 2048
#define NSB 49            // ceil(NN / SCAN_CHUNK)

#define NBK 98            // dst buckets (dst >> 10), 1024 nodes each
#define BCAP 20480        // slots per bucket (avg fill 16.3K, sigma ~126)

// ---- workspace layout (bytes) ----
#define WS_OFF_OFF   0          // 100352 int (pad absorbs tail writes)
#define WS_OFF_CUR   401408     // 100352 int (memset 0; post-scatter = per-node count)
#define WS_OFF_BSUM  802816     // 64 int
#define WS_OFF_GCUR  803072     // 128 int (memset 0)
#define WS_OFF_WCBF  803584     // 128*384 u16 (region reserved for 640)
#define WS_OFF_ESRC  967680     // 1.7M int
#define WS_OFF_GBUF  7768064    // 98*20480*8 = 16056320, then reused as h16
#define WS_OFF_H16   7768064    // NN*128 fp16 = 25600000
#define WS_OFF_NB1   33368064   // NN*128 fp16 = 25600000 (end 58968064)

typedef __attribute__((ext_vector_type(8))) _Float16 f16x8;
typedef __attribute__((ext_vector_type(2))) _Float16 f16x2;
typedef __attribute__((ext_vector_type(4))) float f32x4;

__device__ __forceinline__ unsigned short f2h(float f) {
    _Float16 h = (_Float16)f;                  // v_cvt_f16_f32, RN
    unsigned short s; __builtin_memcpy(&s, &h, 2); return s;
}
__device__ __forceinline__ f16x2 u2h2(unsigned u) {
    f16x2 h; __builtin_memcpy(&h, &u, 4); return h;
}

__global__ void k_prep(const float* __restrict__ h, unsigned int* __restrict__ h16) {
    int i = blockIdx.x * blockDim.x + threadIdx.x;   // 6.4M dwords
    float2 v = reinterpret_cast<const float2*>(h)[i];
    h16[i] = (unsigned)f2h(v.x) | ((unsigned)f2h(v.y) << 16);
}

// pass 1: scan int(deg) per 2048-chunk -> off (local excl), block total -> bsum
__global__ __launch_bounds__(256) void k_scan1(const float* __restrict__ deg,
                                               int* __restrict__ off,
                                               int* __restrict__ bsum) {
    __shared__ int lds[256];
    int t = threadIdx.x, b = blockIdx.x;
    int base = b * SCAN_CHUNK + t * 8;
    int v[8];
    if (base < NN) {   // NN % 8 == 0
        float4 a0 = reinterpret_cast<const float4*>(deg + base)[0];
        float4 a1 = reinterpret_cast<const float4*>(deg + base)[1];
        v[0] = __float2int_rn(a0.x); v[1] = __float2int_rn(a0.y);
        v[2] = __float2int_rn(a0.z); v[3] = __float2int_rn(a0.w);
        v[4] = __float2int_rn(a1.x); v[5] = __float2int_rn(a1.y);
        v[6] = __float2int_rn(a1.z); v[7] = __float2int_rn(a1.w);
    } else {
        #pragma unroll
        for (int j = 0; j < 8; ++j) v[j] = 0;
    }
    int s = 0;
    #pragma unroll
    for (int j = 0; j < 8; ++j) s += v[j];
    lds[t] = s;
    __syncthreads();
    for (int ofs = 1; ofs < 256; ofs <<= 1) {
        int x = (t >= ofs) ? lds[t - ofs] : 0;
        __syncthreads();
        lds[t] += x;
        __syncthreads();
    }
    int excl = (t == 0) ? 0 : lds[t - 1];
    #pragma unroll
    for (int j = 0; j < 8; ++j) { off[base + j] = excl; excl += v[j]; }
    if (t == 255) bsum[b] = lds[255];
}

__global__ void k_scan2(int* __restrict__ bsum) {
    int t = threadIdx.x;
    int v = (t < NSB) ? bsum[t] : 0;
    #pragma unroll
    for (int ofs = 1; ofs < 64; ofs <<= 1) {
        int x = __shfl_up(v, ofs, 64);
        if (t >= ofs) v += x;
    }
    int excl = __shfl_up(v, 1, 64);
    if (t == 0) excl = 0;
    if (t < NSB) bsum[t] = excl;
    if (t == NSB - 1) bsum[NSB] = v;
}

__global__ void k_scan3(int* __restrict__ off, const int* __restrict__ bsum) {
    int i = blockIdx.x * blockDim.x + threadIdx.x;
    if (i < NN) off[i] += bsum[i >> 11];
    if (i == 0) off[NN] = bsum[NSB];
}

// binning pass A: edges -> 98 dst-range buckets, LDS-aggregated ranks
__global__ __launch_bounds__(256) void k_bin(const int* __restrict__ src,
                                             const int* __restrict__ dst,
                                             int* __restrict__ gcur,
                                             int2* __restrict__ gbuf) {
    __shared__ int bcnt[NBK];
    __shared__ int bbase[NBK];
    int t = threadIdx.x;
    if (t < NBK) bcnt[t] = 0;
    __syncthreads();
    int e0 = blockIdx.x * 2048;
    int s[8], d[8], r[8];
    #pragma unroll
    for (int it = 0; it < 8; ++it) {
        int e = e0 + it * 256 + t;
        bool ok = e < NE;
        s[it] = ok ? src[e] : 0;
        d[it] = ok ? dst[e] : -1;
        r[it] = ok ? atomicAdd(&bcnt[d[it] >> 10], 1) : 0;
    }
    __syncthreads();
    if (t < NBK) bbase[t] = atomicAdd(&gcur[t], bcnt[t]);
    __syncthreads();
    #pragma unroll
    for (int it = 0; it < 8; ++it) {
        if (d[it] >= 0) {
            int bk = d[it] >> 10;
            gbuf[(size_t)bk * BCAP + bbase[bk] + r[it]] = make_int2(s[it], d[it]);
        }
    }
}

// scatter pass B: one block per bucket; esrc/cur writes stay in a ~70KB L2 window
__global__ __launch_bounds__(1024) void k_scatter2(const int2* __restrict__ gbuf,
                                                   const int* __restrict__ gcur,
                                                   const int* __restrict__ off,
                                                   int* __restrict__ cur,
                                                   int* __restrict__ esrc) {
    int b = blockIdx.x;
    int nb = gcur[b];
    const int2* bb = gbuf + (size_t)b * BCAP;
    for (int i = threadIdx.x; i < nb; i += 1024) {
        int2 e = bb[i];
        int p = off[e.y] + atomicAdd(&cur[e.y], 1);
        esrc[p] = e.x;
    }
}

// combined weights -> fp16, [o][384]: segs {b1, b2, b3}
// b1 = s0*Wself + s2*Whp (h); b2 = s1*Wnb1 - s2*Whp (nb1); b3 = s3*Wnb2 (nb2)
__global__ void k_weights(const float* __restrict__ Ws, const float* __restrict__ W1,
                          const float* __restrict__ Whp, const float* __restrict__ W2,
                          const float* __restrict__ logits, unsigned short* __restrict__ wcbf) {
    int idx = blockIdx.x * blockDim.x + threadIdx.x;
    if (idx >= D * D) return;
    int o = idx >> 7, k = idx & 127;
    float s0 = 2.f / (1.f + __expf(-logits[0]));
    float s1 = 2.f / (1.f + __expf(-logits[1]));
    float s2 = 2.f / (1.f + __expf(-logits[2]));
    float s3 = 2.f / (1.f + __expf(-logits[3]));
    unsigned short b1 = f2h(s0 * Ws[idx] + s2 * Whp[idx]);
    unsigned short b2 = f2h(s1 * W1[idx] - s2 * Whp[idx]);
    unsigned short b3 = f2h(s3 * W2[idx]);
    size_t base = (size_t)o * KTOT + k;
    wcbf[base]       = b1;   // h
    wcbf[base + 128] = b2;   // nb1
    wcbf[base + 256] = b3;   // nb2
}

// one wave per node; lane owns 2 dims packed in one dword (fp16 pair).
// Inner loop: 16-wide predicated steps — 16 uniform readlanes + 16 loads all
// in flight (clamped src index, uniform-cond zero for idx>=m). No serial tail:
// a typical deg~16 node is one load round-trip at MLP=16.
// INTERLEAVED=true: write nb2 into the second half of each 128-float out row.
template <bool INTERLEAVED>
__global__ __launch_bounds__(256) void k_hop(const unsigned int* __restrict__ in,
                                             unsigned int* __restrict__ outp,
                                             const int* __restrict__ off,
                                             const int* __restrict__ cnt_arr,
                                             const int* __restrict__ esrc,
                                             const float* __restrict__ deg) {
    int w = (blockIdx.x * blockDim.x + threadIdx.x) >> 6;
    int lane = threadIdx.x & 63;
    int beg = __builtin_amdgcn_readfirstlane(off[w]);
    int cnt = __builtin_amdgcn_readfirstlane(cnt_arr[w]);
    float ax = 0.f, ay = 0.f;
    for (int bs = 0; bs < cnt; bs += 64) {
        int m = cnt - bs; if (m > 64) m = 64;
        int ev = esrc[beg + bs + (lane < m ? lane : 0)];
        for (int j = 0; j < m; j += 16) {
            unsigned u[16];
            #pragma unroll
            for (int k = 0; k < 16; ++k) {
                int idx = j + k;                               // wave-uniform
                int s = __builtin_amdgcn_readlane(ev, idx < m ? idx : 0);
                u[k] = in[(size_t)s * 64 + lane];              // SGPR base + lane
            }
            #pragma unroll
            for (int k = 0; k < 16; ++k) {
                if (j + k >= m) u[k] = 0u;                     // uniform cond
                f16x2 v = u2h2(u[k]);
                ax += (float)v.x; ay += (float)v.y;
            }
        }
    }
    float inv = 1.0f / deg[w];
    ax *= inv; ay *= inv;
    unsigned pk = (unsigned)f2h(ax) | ((unsigned)f2h(ay) << 16);
    if (INTERLEAVED) outp[(size_t)w * 128 + 64 + lane] = pk;
    else             outp[(size_t)w * 64 + lane] = pk;
}

// MFMA GEMM (M=32/block, N=128, K=384 in two 192-K LDS chunks) + fused LN.
// Chunk 0 = [h | nb1[0:64]], chunk 1 = [nb1[64:128] | nb2]  (matches wcbf order).
// 12.8KB LDS Xs -> 8 blocks/CU (wave-capped). LN epilogue in registers.
__global__ __launch_bounds__(256) void k_gemm_ln(
    const unsigned int* __restrict__ h16,
    const unsigned int* __restrict__ nb1u,
    const unsigned short* __restrict__ wcbf, const float* __restrict__ bias,
    const float* __restrict__ gamma, const float* __restrict__ beta,
    float* __restrict__ out) {
    __shared__ __align__(16) unsigned short Xs[32 * PITCH_US];   // 12800 B
    __shared__ float part_s[4][32];
    __shared__ float part_q[4][32];
    __shared__ float mu_s[32], rs_s[32];
    unsigned int* Xs_u = reinterpret_cast<unsigned int*>(Xs);
    const unsigned int* out_u = reinterpret_cast<const unsigned int*>(out);

    const int t = threadIdx.x;
    const int wv = t >> 6, lane = t & 63;
    const int lm = lane & 15, quad = lane >> 4;
    const int node0 = blockIdx.x * 32;
    const int obase = wv * 32;

    f32x4 acc[2][2] = {};

    #pragma unroll
    for (int c = 0; c < 2; ++c) {
        if (c == 0) {
            // ---- stage chunk 0: h (dw 0..63), nb1[0:32dw] (64..95)
            #pragma unroll
            for (int it = 0; it < 8; ++it) {
                int i = t + 256 * it;
                int row = i >> 6, d = i & 63;
                Xs_u[row * PITCH_DW + d] = h16[(size_t)(node0 + row) * 64 + d];
            }
            #pragma unroll
            for (int it = 0; it < 4; ++it) {
                int i = t + 256 * it;
                int row = i >> 5, d = i & 31;
                Xs_u[row * PITCH_DW + 64 + d] = nb1u[(size_t)(node0 + row) * 64 + d];
            }
        } else {
            // ---- stage chunk 1: nb1[32:64dw] (dw 0..31), nb2 (32..95, from out rows)
            #pragma unroll
            for (int it = 0; it < 4; ++it) {
                int i = t + 256 * it;
                int row = i >> 5, d = i & 31;
                Xs_u[row * PITCH_DW + d] = nb1u[(size_t)(node0 + row) * 64 + 32 + d];
            }
            #pragma unroll
            for (int it = 0; it < 8; ++it) {
                int i = t + 256 * it;
                int row = i >> 6, d = i & 63;
                Xs_u[row * PITCH_DW + 32 + d] = out_u[(size_t)(node0 + row) * 128 + 64 + d];
            }
        }
        __syncthreads();

        f16x8 bfr[2][6];
        #pragma unroll
        for (int nt = 0; nt < 2; ++nt) {
            const unsigned short* wp =
                wcbf + (size_t)(obase + nt * 16 + lm) * KTOT + c * 192 + quad * 8;
            #pragma unroll
            for (int s = 0; s < 6; ++s)
                bfr[nt][s] = *reinterpret_cast<const f16x8*>(wp + s * 32);
        }
        #pragma unroll
        for (int s = 0; s < 6; ++s) {
            int koff = s * 32 + quad * 8;
            f16x8 a0 = *reinterpret_cast<const f16x8*>(&Xs[(0 * 16 + lm) * PITCH_US + koff]);
            f16x8 a1 = *reinterpret_cast<const f16x8*>(&Xs[(1 * 16 + lm) * PITCH_US + koff]);
            acc[0][0] = __builtin_amdgcn_mfma_f32_16x16x32_f16(a0, bfr[0][s], acc[0][0], 0, 0, 0);
            acc[0][1] = __builtin_amdgcn_mfma_f32_16x16x32_f16(a0, bfr[1][s], acc[0][1], 0, 0, 0);
            acc[1][0] = __builtin_amdgcn_mfma_f32_16x16x32_f16(a1, bfr[0][s], acc[1][0], 0, 0, 0);
            acc[1][1] = __builtin_amdgcn_mfma_f32_16x16x32_f16(a1, bfr[1][s], acc[1][1], 0, 0, 0);
        }
        __syncthreads();   // safe to restage / proceed
    }

    // ---- LN: add bias; per-row partial sums via lm-butterfly; cross-wave via LDS
    float bv0 = bias[obase + lm], bv1 = bias[obase + 16 + lm];
    #pragma unroll
    for (int mt = 0; mt < 2; ++mt) {
        float s[4], q[4];
        #pragma unroll
        for (int r = 0; r < 4; ++r) {
            float v0 = acc[mt][0][r] + bv0;
            float v1 = acc[mt][1][r] + bv1;
            acc[mt][0][r] = v0;  acc[mt][1][r] = v1;
            s[r] = v0 + v1;
            q[r] = v0 * v0 + v1 * v1;
        }
        #pragma unroll
        for (int off = 1; off < 16; off <<= 1) {
            #pragma unroll
            for (int r = 0; r < 4; ++r) {
                s[r] += __shfl_xor(s[r], off, 64);
                q[r] += __shfl_xor(q[r], off, 64);
            }
        }
        if (lm == 0) {
            #pragma unroll
            for (int r = 0; r < 4; ++r) {
                part_s[wv][mt * 16 + quad * 4 + r] = s[r];
                part_q[wv][mt * 16 + quad * 4 + r] = q[r];
            }
        }
    }
    __syncthreads();
    if (t < 32) {
        float s = part_s[0][t] + part_s[1][t] + part_s[2][t] + part_s[3][t];
        float q = part_q[0][t] + part_q[1][t] + part_q[2][t] + part_q[3][t];
        float m = s * (1.f / 128.f);
        float var = q * (1.f / 128.f) - m * m;
        mu_s[t] = m;
        rs_s[t] = rsqrtf(var + LN_EPS);
    }
    __syncthreads();

    float g0 = gamma[obase + lm], g1 = gamma[obase + 16 + lm];
    float e0 = beta[obase + lm],  e1 = beta[obase + 16 + lm];
    #pragma unroll
    for (int mt = 0; mt < 2; ++mt) {
        #pragma unroll
        for (int r = 0; r < 4; ++r) {
            int lrow = mt * 16 + quad * 4 + r;
            float mu = mu_s[lrow], rs = rs_s[lrow];
            size_t ro = (size_t)(node0 + lrow) * D;
            out[ro + obase + lm]      = (acc[mt][0][r] - mu) * rs * g0 + e0;
            out[ro + obase + 16 + lm] = (acc[mt][1][r] - mu) * rs * g1 + e1;
        }
    }
}

extern "C" void kernel_launch(void* const* d_in, const int* in_sizes, int n_in,
                              void* d_out, int out_size, void* d_ws, size_t ws_size,
                              hipStream_t stream) {
    const float* h      = (const float*)d_in[0];
    const int*   ei     = (const int*)d_in[1];
    const float* deg    = (const float*)d_in[2];
    const float* Wself  = (const float*)d_in[3];
    const float* Wnb1   = (const float*)d_in[4];
    const float* Whp    = (const float*)d_in[5];
    const float* Wnb2   = (const float*)d_in[6];
    const float* bias   = (const float*)d_in[7];
    const float* logits = (const float*)d_in[8];
    const float* gamma  = (const float*)d_in[9];
    const float* beta   = (const float*)d_in[10];
    float* out = (float*)d_out;

    char* ws = (char*)d_ws;
    int* off                 = (int*)(ws + WS_OFF_OFF);
    int* cur                 = (int*)(ws + WS_OFF_CUR);
    int* bsum                = (int*)(ws + WS_OFF_BSUM);
    int* gcur                = (int*)(ws + WS_OFF_GCUR);
    unsigned short* wcbf     = (unsigned short*)(ws + WS_OFF_WCBF);
    int* esrc                = (int*)(ws + WS_OFF_ESRC);
    int2* gbuf               = (int2*)(ws + WS_OFF_GBUF);
    unsigned int* h16        = (unsigned int*)(ws + WS_OFF_H16);
    unsigned int* nb1u       = (unsigned int*)(ws + WS_OFF_NB1);

    const int* src = ei;
    const int* dst = ei + NE;

    hipMemsetAsync(cur, 0, NN * sizeof(int), stream);
    hipMemsetAsync(gcur, 0, NBK * sizeof(int), stream);

    k_weights<<<64, 256, 0, stream>>>(Wself, Wnb1, Whp, Wnb2, logits, wcbf);
    k_scan1<<<NSB, 256, 0, stream>>>(deg, off, bsum);
    k_scan2<<<1, 64, 0, stream>>>(bsum);
    k_scan3<<<(NN + 255) / 256, 256, 0, stream>>>(off, bsum);
    k_bin<<<(NE + 2047) / 2048, 256, 0, stream>>>(src, dst, gcur, gbuf);
    k_scatter2<<<NBK, 1024, 0, stream>>>(gbuf, gcur, off, cur, esrc);

    // prep AFTER scatter2: h16 overlays the (now dead) gbuf region
    k_prep<<<25000, 256, 0, stream>>>(h, h16);

    // hop1: gather h (fp16) -> nb1 (fp16, ws)
    k_hop<false><<<(NN * 64) / 256, 256, 0, stream>>>(h16, nb1u, off, cur, esrc, deg);
    // hop2: gather nb1 (fp16) -> nb2 (fp16, interleaved into out rows' 2nd half)
    k_hop<true><<<(NN * 64) / 256, 256, 0, stream>>>(nb1u, (unsigned int*)out, off, cur, esrc, deg);

    k_gemm_ln<<<NN / 32, 256, 0, stream>>>(h16, nb1u, wcbf, bias, gamma, beta, out);
}